// Round 13
// baseline (777.560 us; speedup 1.0000x reference)
//
#include <hip/hip_runtime.h>
#include <hip/hip_bf16.h>

// DeepGCN forward (R12 = R9 structure + 128-thread barrier-free spmm):
//   memset(zeros) -> hist -> scan1/2/3(+gcur) -> bin_a -> bin_b -> weights_k ->
//   col_reduce -> finalize<BN> -> L0 GEMM (composite W_in@W0) ->
//   4x [ spmm(128-thr, no-LDS, per-wave atomic stats) -> finalize<PN> ->
//        GEMM with fused PN+ReLU+residual pre-stage ] ; last GEMM = fc_out.
// R11 post-mortem: in-block finalize in every GEMM block (serial 64-slot reduce +
//   2 barriers before staging) cost ~11us net vs 5 tiny finalize dispatches -> revert.
// R12: spmm blocks 256->128 threads, stats via per-wave shuffle + direct atomicAdd
//   (no LDS, no barrier) -> occupancy experiment: 16 blk/CU x 2 waves = 32 waves/CU.

constexpr int DD = 128;

struct alignas(16) f4 { float v[4]; };
typedef unsigned short ushort;
typedef unsigned int uint;
typedef short short8 __attribute__((ext_vector_type(8)));
typedef float f32x4 __attribute__((ext_vector_type(4)));

__device__ inline ushort f2bf(float f) {   // RNE f32->bf16
    uint u = __float_as_uint(f);
    u += 0x7fffu + ((u >> 16) & 1u);
    return (ushort)(u >> 16);
}
__device__ inline void bf8_unpack(uint4 u, float* v) {
    v[0] = __uint_as_float(u.x << 16); v[1] = __uint_as_float(u.x & 0xffff0000u);
    v[2] = __uint_as_float(u.y << 16); v[3] = __uint_as_float(u.y & 0xffff0000u);
    v[4] = __uint_as_float(u.z << 16); v[5] = __uint_as_float(u.z & 0xffff0000u);
    v[6] = __uint_as_float(u.w << 16); v[7] = __uint_as_float(u.w & 0xffff0000u);
}
__device__ inline uint4 bf8_pack(const float* v) {
    uint4 o;
    o.x = (uint)f2bf(v[0]) | ((uint)f2bf(v[1]) << 16);
    o.y = (uint)f2bf(v[2]) | ((uint)f2bf(v[3]) << 16);
    o.z = (uint)f2bf(v[4]) | ((uint)f2bf(v[5]) << 16);
    o.w = (uint)f2bf(v[6]) | ((uint)f2bf(v[7]) << 16);
    return o;
}

// ---------------- BN stats over x_in: per-block partials ----------------
__global__ __launch_bounds__(256) void col_reduce_k(const float* __restrict__ X, int n,
    float* __restrict__ psum, float* __restrict__ psq)
{
    int c = threadIdx.x & (DD - 1);
    int half = threadIdx.x >> 7;
    int rows_per_blk = (n + gridDim.x - 1) / gridDim.x;
    int r0 = blockIdx.x * rows_per_blk;
    int r1 = min(n, r0 + rows_per_blk);
    float s = 0.f, ss = 0.f;
    for (int r = r0 + half; r < r1; r += 2) {
        float v = X[(size_t)r * DD + c];
        s += v; ss += v * v;
    }
    __shared__ float ls[256], lq[256];
    ls[threadIdx.x] = s; lq[threadIdx.x] = ss;
    __syncthreads();
    if (half == 0) {
        psum[blockIdx.x * DD + c] = ls[c] + ls[c + 128];
        psq [blockIdx.x * DD + c] = lq[c] + lq[c + 128];
    }
}

// ---------------- finalize (BN or PN) ----------------
template<bool BN>
__global__ __launch_bounds__(1024) void finalize_k(const float* __restrict__ psum,
    const float* __restrict__ psq, int nblk, int n,
    const float* __restrict__ gamma, const float* __restrict__ beta,
    float* __restrict__ AB)
{
    const int c = threadIdx.x & (DD - 1);
    const int g = threadIdx.x >> 7;   // 0..7
    float s = 0.f, ss = 0.f;
    for (int b = g; b < nblk; b += 8) {
        s  += psum[b * DD + c];
        ss += psq [b * DD + c];
    }
    __shared__ float Ls[8][DD], Lq[8][DD];
    Ls[g][c] = s; Lq[g][c] = ss;
    __syncthreads();
    float ts = 0.f, tss = 0.f;
    #pragma unroll
    for (int k = 0; k < 8; k++) { ts += Ls[k][c]; tss += Lq[k][c]; }
    float mu = ts / (float)n;
    if (BN) {
        if (threadIdx.x < DD) {
            float var = tss / (float)n - mu * mu;
            float a = gamma[c] * rsqrtf(var + 1e-5f);
            AB[c] = a;
            AB[DD + c] = beta[c] - mu * a;
        }
    } else {
        float cent = tss - (float)n * mu * mu;
        __syncthreads();
        if (g == 0) Ls[0][c] = cent;
        __syncthreads();
        for (int off = 64; off > 0; off >>= 1) {
            if (threadIdx.x < off) Ls[0][threadIdx.x] += Ls[0][threadIdx.x + off];
            __syncthreads();
        }
        if (threadIdx.x < DD) {
            float inv = rsqrtf(1e-6f + Ls[0][0] / (float)n);
            AB[c] = inv;
            AB[DD + c] = -mu * inv;
        }
    }
}

// ---------------- all weight prep in one kernel (role by blockIdx) ----------------
__global__ __launch_bounds__(256) void weights_k(const float* __restrict__ gc_w,
    const float* __restrict__ fc_in_w, const float* __restrict__ fc_in_b,
    const float* __restrict__ fc_out_w,
    ushort* __restrict__ Wt, ushort* __restrict__ Wtc, ushort* __restrict__ WtO,
    float* __restrict__ bc)
{
    const int b = blockIdx.x;
    const int t = threadIdx.x;
    if (b < 64) {
        int w = b >> 4, tile = b & 15;
        int tr = (tile >> 2) * 32, tc = (tile & 3) * 32;
        const float* W = gc_w + (size_t)w * DD * DD;
        ushort* Wo = Wt + (size_t)w * DD * DD;
        __shared__ float tls[32][33];
        int tx = t & 31, ty = t >> 5;  // 32 x 8
        #pragma unroll
        for (int j = 0; j < 32; j += 8)
            tls[ty + j][tx] = W[(size_t)(tr + ty + j) * DD + tc + tx];
        __syncthreads();
        #pragma unroll
        for (int j = 0; j < 32; j += 8)
            Wo[(size_t)(tc + ty + j) * DD + (tr + tx)] = f2bf(tls[tx][ty + j]);
    } else if (b == 64) {
        for (int i = t; i < 48 * DD; i += 256) {
            int nn = i >> 7, k = i & 127;
            float v = (nn < 40) ? fc_out_w[(size_t)k * 40 + nn] : 0.f;
            WtO[i] = f2bf(v);
        }
    } else if (b == 65) {
        if (t < DD) {
            float acc = 0.f;
            for (int j = 0; j < DD; j++) acc += fc_in_b[j] * gc_w[(size_t)j * DD + t];
            bc[t] = acc;
        }
    } else {
        int idx = (b - 66) * 256 + t;
        int nn = idx & 127, k = idx >> 7;
        float acc = 0.f;
        for (int j = 0; j < DD; j++)
            acc += fc_in_w[(size_t)k * DD + j] * gc_w[(size_t)j * DD + nn];
        Wtc[(size_t)nn * DD + k] = f2bf(acc);
    }
}

// ---------------- MFMA GEMM with fused pre-stage (R9 version) ----------------
// PRE: 1=f32 BN affine, 2=bf16-in PN relu(x*A+B), 3=PN + residual (bf16 X)
template<int PRE, int NCOLF, int NCOLW, bool BIAS, bool OUTBF, bool WRITEX>
__global__ __launch_bounds__(256) void gemm_mfma_k(const void* __restrict__ INv,
    const ushort* __restrict__ Wt, const float* __restrict__ AB,
    const float* __restrict__ bias, void* __restrict__ Xresv,
    void* __restrict__ Yout, int ystride, int n)
{
    __shared__ short xs[64][136];            // [m][k] bf16 (pad 136)
    __shared__ short ws[NCOLF * 16][136];    // [n][k] bf16
    __shared__ float bias_s[DD];
    const int t = threadIdx.x;
    if (BIAS && t < NCOLW) bias_s[t] = bias[t];

    const int row0 = blockIdx.x * 64;
    if (PRE <= 1) {
        const float* IN = (const float*)INv;
        for (int i = t; i < 64 * 32; i += 256) {
            int m = i >> 5, koff = (i & 31) << 2;
            int r = row0 + m;
            f4 v; v.v[0] = v.v[1] = v.v[2] = v.v[3] = 0.f;
            if (r < n) {
                v = *reinterpret_cast<const f4*>(IN + (size_t)r * DD + koff);
                #pragma unroll
                for (int j = 0; j < 4; j++) v.v[j] = v.v[j] * AB[koff + j] + AB[DD + koff + j];
            }
            uint2 p;
            p.x = (uint)f2bf(v.v[0]) | ((uint)f2bf(v.v[1]) << 16);
            p.y = (uint)f2bf(v.v[2]) | ((uint)f2bf(v.v[3]) << 16);
            *reinterpret_cast<uint2*>(&xs[m][koff]) = p;
        }
    } else {
        const ushort* IN = (const ushort*)INv;
        ushort* Xres = (ushort*)Xresv;
        for (int i = t; i < 64 * 16; i += 256) {
            int m = i >> 4, k8 = (i & 15) << 3;
            int r = row0 + m;
            float v[8];
            if (r < n) {
                uint4 u = *reinterpret_cast<const uint4*>(IN + (size_t)r * DD + k8);
                bf8_unpack(u, v);
                #pragma unroll
                for (int j = 0; j < 8; j++)
                    v[j] = fmaxf(v[j] * AB[k8 + j] + AB[DD + k8 + j], 0.f);
                if (PRE == 3) {
                    uint4 xo = *reinterpret_cast<const uint4*>(Xres + (size_t)r * DD + k8);
                    float xov[8]; bf8_unpack(xo, xov);
                    #pragma unroll
                    for (int j = 0; j < 8; j++) v[j] += xov[j];
                }
                uint4 pk = bf8_pack(v);
                if (WRITEX)
                    *reinterpret_cast<uint4*>(Xres + (size_t)r * DD + k8) = pk;
                *reinterpret_cast<uint4*>(&xs[m][k8]) = pk;
            } else {
                uint4 z; z.x = z.y = z.z = z.w = 0u;
                *reinterpret_cast<uint4*>(&xs[m][k8]) = z;
            }
        }
    }
    for (int i = t; i < NCOLF * 256; i += 256) {
        int nn = i >> 4, koff = (i & 15) << 3;
        *reinterpret_cast<uint4*>(&ws[nn][koff]) =
            *reinterpret_cast<const uint4*>(Wt + (size_t)nn * DD + koff);
    }
    __syncthreads();

    const int wave = t >> 6, lane = t & 63, fr = lane & 15, g = lane >> 4;
    f32x4 acc[NCOLF];
    #pragma unroll
    for (int c = 0; c < NCOLF; c++) acc[c] = (f32x4){0.f, 0.f, 0.f, 0.f};

    #pragma unroll 2
    for (int ks = 0; ks < 4; ks++) {
        int k0 = ks * 32 + g * 8;
        short8 a = *reinterpret_cast<const short8*>(&xs[wave * 16 + fr][k0]);
        #pragma unroll
        for (int c = 0; c < NCOLF; c++) {
            short8 b = *reinterpret_cast<const short8*>(&ws[c * 16 + fr][k0]);
            // mfma(W_frag, X_frag): out lane&15 = X-row (m), g*4+reg = W-col (n)
            acc[c] = __builtin_amdgcn_mfma_f32_16x16x32_bf16(b, a, acc[c], 0, 0, 0);
        }
    }

    const int row = row0 + wave * 16 + fr;
    if (row < n) {
        #pragma unroll
        for (int c = 0; c < NCOLF; c++) {
            int n0 = c * 16 + g * 4;
            if (OUTBF) {
                float b0 = BIAS ? bias_s[n0 + 0] : 0.f, b1 = BIAS ? bias_s[n0 + 1] : 0.f;
                float b2 = BIAS ? bias_s[n0 + 2] : 0.f, b3 = BIAS ? bias_s[n0 + 3] : 0.f;
                uint2 o;
                o.x = (uint)f2bf(acc[c][0] + b0) | ((uint)f2bf(acc[c][1] + b1) << 16);
                o.y = (uint)f2bf(acc[c][2] + b2) | ((uint)f2bf(acc[c][3] + b3) << 16);
                *reinterpret_cast<uint2*>((ushort*)Yout + (size_t)row * DD + n0) = o;
            } else if (n0 + 3 < NCOLW) {
                f4 o;
                #pragma unroll
                for (int j = 0; j < 4; j++)
                    o.v[j] = acc[c][j] + (BIAS ? bias_s[n0 + j] : 0.f);
                *reinterpret_cast<f4*>((float*)Yout + (size_t)row * ystride + n0) = o;
            }
        }
    }
}

// ---------------- CSR build ----------------
__global__ __launch_bounds__(256) void hist_k(const int* __restrict__ erow,
    int* __restrict__ deg, int e)
{
    int i = blockIdx.x * 256 + threadIdx.x;
    if (i < e) atomicAdd(&deg[erow[i]], 1);
}

constexpr int SCAN_TILE = 1024;
constexpr int BSH = 9;                 // 512-row buckets

__global__ __launch_bounds__(256) void scan1_k(const int* __restrict__ deg,
    int* __restrict__ local, int* __restrict__ bsum, int n)
{
    const int t = threadIdx.x;
    const int base = blockIdx.x * SCAN_TILE + t * 4;
    int v0 = 0, v1 = 0, v2 = 0, v3 = 0;
    if (base + 3 < n) {
        int4 v = *reinterpret_cast<const int4*>(deg + base);
        v0 = v.x; v1 = v.y; v2 = v.z; v3 = v.w;
    } else {
        if (base + 0 < n) v0 = deg[base + 0];
        if (base + 1 < n) v1 = deg[base + 1];
        if (base + 2 < n) v2 = deg[base + 2];
        if (base + 3 < n) v3 = deg[base + 3];
    }
    int s = v0 + v1 + v2 + v3;
    __shared__ int ps[256];
    ps[t] = s;
    __syncthreads();
    for (int off = 1; off < 256; off <<= 1) {
        int add = (t >= off) ? ps[t - off] : 0;
        __syncthreads();
        ps[t] += add;
        __syncthreads();
    }
    int excl = (t > 0) ? ps[t - 1] : 0;
    int o0 = excl, o1 = excl + v0, o2 = o1 + v1, o3 = o2 + v2;
    if (base + 3 < n) {
        int4 o; o.x = o0; o.y = o1; o.z = o2; o.w = o3;
        *reinterpret_cast<int4*>(local + base) = o;
    } else {
        if (base + 0 < n) local[base + 0] = o0;
        if (base + 1 < n) local[base + 1] = o1;
        if (base + 2 < n) local[base + 2] = o2;
        if (base + 3 < n) local[base + 3] = o3;
    }
    if (t == 255) bsum[blockIdx.x] = ps[255];
}

__global__ __launch_bounds__(256) void scan2_k(const int* __restrict__ bsum,
    int* __restrict__ bpre, int nb, int* __restrict__ rowptr, int n)
{
    const int t = threadIdx.x;
    __shared__ int ps[256];
    ps[t] = (t < nb) ? bsum[t] : 0;
    __syncthreads();
    for (int off = 1; off < 256; off <<= 1) {
        int add = (t >= off) ? ps[t - off] : 0;
        __syncthreads();
        ps[t] += add;
        __syncthreads();
    }
    if (t < nb) bpre[t] = (t > 0) ? ps[t - 1] : 0;
    if (t == 255) rowptr[n] = ps[255];
}

// also writes gcur[] at 512-row bucket boundaries (folded gcur_init)
__global__ __launch_bounds__(256) void scan3_k(const int* __restrict__ local,
    const int* __restrict__ bpre, int* __restrict__ rowptr, int* __restrict__ cursor,
    int* __restrict__ gcur, int n)
{
    const int base = blockIdx.x * SCAN_TILE + threadIdx.x * 4;
    const int p = bpre[blockIdx.x];
    if (base + 3 < n) {
        int4 v = *reinterpret_cast<const int4*>(local + base);
        v.x += p; v.y += p; v.z += p; v.w += p;
        *reinterpret_cast<int4*>(rowptr + base) = v;
        *reinterpret_cast<int4*>(cursor + base) = v;
        if ((base & 511) == 0) gcur[base >> BSH] = v.x;
    } else {
        #pragma unroll
        for (int j = 0; j < 4; j++)
            if (base + j < n) {
                int v = local[base + j] + p;
                rowptr[base + j] = v;
                cursor[base + j] = v;
                if (((base + j) & 511) == 0) gcur[(base + j) >> BSH] = v;
            }
    }
}

// pass A: bin edges by 512-row bucket (LDS rank; bucket-contiguous 8B writes)
__global__ __launch_bounds__(256) void bin_a_k(const int* __restrict__ erow,
    const int* __restrict__ ecol, const float* __restrict__ evalv,
    int* __restrict__ gcur, uint2* __restrict__ binned, int e)
{
    __shared__ int cnt[128];
    __shared__ int base[128];
    const int t = threadIdx.x;
    if (t < 128) cnt[t] = 0;
    __syncthreads();
    const int i0 = blockIdx.x * 2048 + t * 8;
    int rw[8], cl[8], rk[8];
    float vl[8];
    #pragma unroll
    for (int j = 0; j < 8; j++) {
        int idx = i0 + j;
        if (idx < e) { rw[j] = erow[idx]; cl[j] = ecol[idx]; vl[j] = evalv[idx]; }
        else rw[j] = -1;
    }
    #pragma unroll
    for (int j = 0; j < 8; j++)
        if (rw[j] >= 0) rk[j] = atomicAdd(&cnt[rw[j] >> BSH], 1);
    __syncthreads();
    if (t < 128) base[t] = cnt[t] ? atomicAdd(&gcur[t], cnt[t]) : 0;
    __syncthreads();
    #pragma unroll
    for (int j = 0; j < 8; j++) {
        if (rw[j] >= 0) {
            int b = rw[j] >> BSH, rl = rw[j] & ((1 << BSH) - 1);
            uint2 pr;
            pr.x = (uint)cl[j] | ((uint)rl << 16);
            pr.y = __float_as_uint(vl[j]);
            binned[base[b] + rk[j]] = pr;
        }
    }
}

// pass B: within-bucket scatter to CSR position (dest region ~64KB -> L2-resident)
__global__ __launch_bounds__(256) void bin_b_k(const uint2* __restrict__ binned,
    const int* __restrict__ rowptr, int* __restrict__ cursor,
    int2* __restrict__ cpair, int n)
{
    const int b = blockIdx.x;
    const int r0 = min(b << BSH, n), r1 = min((b + 1) << BSH, n);
    const int p0 = rowptr[r0], p1 = rowptr[r1];
    for (int p = p0 + threadIdx.x; p < p1; p += 256) {
        uint2 u = binned[p];
        int r = (b << BSH) + (int)(u.x >> 16);
        int pos = atomicAdd(&cursor[r], 1);
        int2 pr; pr.x = (int)(u.x & 0xffffu); pr.y = (int)u.y;
        cpair[pos] = pr;
    }
}

// ---------------- SpMM (bf16 gather) + per-wave atomic stats ----------------
// R12: 128-thread blocks (2 waves, 8 rows), NO LDS, NO barrier. Stats reduced
// within-wave via shuffle; lanes<16 of each wave atomicAdd into 64 slot-sets.
__global__ __launch_bounds__(128) void spmm_fused_k(const int* __restrict__ rowptr,
    const int2* __restrict__ cpair, const ushort* __restrict__ H,
    ushort* __restrict__ AGG, float* __restrict__ psum, float* __restrict__ psq, int n)
{
    const int t = threadIdx.x;
    const int gid = blockIdx.x * 128 + t;
    const int r = gid >> 4;
    const int q = t & 15;
    float a[8];
    #pragma unroll
    for (int j = 0; j < 8; j++) a[j] = 0.f;

    if (r < n) {
        int p0 = rowptr[r], p1 = rowptr[r + 1];
        const ushort* Hq = H + q * 8;
        int p = p0;
        for (; p + 8 <= p1; p += 8) {             // 8-deep MLP
            int2 c[8];
            #pragma unroll
            for (int j = 0; j < 8; j++) c[j] = cpair[p + j];
            uint4 u[8];
            #pragma unroll
            for (int j = 0; j < 8; j++)
                u[j] = *reinterpret_cast<const uint4*>(Hq + (size_t)c[j].x * DD);
            #pragma unroll
            for (int j = 0; j < 8; j++) {
                float v = __int_as_float(c[j].y);
                a[0] = fmaf(v, __uint_as_float(u[j].x << 16), a[0]);
                a[1] = fmaf(v, __uint_as_float(u[j].x & 0xffff0000u), a[1]);
                a[2] = fmaf(v, __uint_as_float(u[j].y << 16), a[2]);
                a[3] = fmaf(v, __uint_as_float(u[j].y & 0xffff0000u), a[3]);
                a[4] = fmaf(v, __uint_as_float(u[j].z << 16), a[4]);
                a[5] = fmaf(v, __uint_as_float(u[j].z & 0xffff0000u), a[5]);
                a[6] = fmaf(v, __uint_as_float(u[j].w << 16), a[6]);
                a[7] = fmaf(v, __uint_as_float(u[j].w & 0xffff0000u), a[7]);
            }
        }
        if (p + 4 <= p1) {                        // 4-deep
            int2 c[4];
            #pragma unroll
            for (int j = 0; j < 4; j++) c[j] = cpair[p + j];
            uint4 u[4];
            #pragma unroll
            for (int j = 0; j < 4; j++)
                u[j] = *reinterpret_cast<const uint4*>(Hq + (size_t)c[j].x * DD);
            #pragma unroll
            for (int j = 0; j < 4; j++) {
                float v = __int_as_float(c[j].y);
                a[0] = fmaf(v, __uint_as_float(u[j].x << 16), a[0]);
                a[1] = fmaf(v, __uint_as_float(u[j].x & 0xffff0000u), a[1]);
                a[2] = fmaf(v, __uint_as_float(u[j].y << 16), a[2]);
                a[3] = fmaf(v, __uint_as_float(u[j].y & 0xffff0000u), a[3]);
                a[4] = fmaf(v, __uint_as_float(u[j].z << 16), a[4]);
                a[5] = fmaf(v, __uint_as_float(u[j].z & 0xffff0000u), a[5]);
                a[6] = fmaf(v, __uint_as_float(u[j].w << 16), a[6]);
                a[7] = fmaf(v, __uint_as_float(u[j].w & 0xffff0000u), a[7]);
            }
            p += 4;
        }
        for (; p < p1; p++) {                     // tail
            int2 cv = cpair[p];
            float v = __int_as_float(cv.y);
            uint4 u = *reinterpret_cast<const uint4*>(Hq + (size_t)cv.x * DD);
            a[0] = fmaf(v, __uint_as_float(u.x << 16), a[0]);
            a[1] = fmaf(v, __uint_as_float(u.x & 0xffff0000u), a[1]);
            a[2] = fmaf(v, __uint_as_float(u.y << 16), a[2]);
            a[3] = fmaf(v, __uint_as_float(u.y & 0xffff0000u), a[3]);
            a[4] = fmaf(v, __uint_as_float(u.z << 16), a[4]);
            a[5] = fmaf(v, __uint_as_float(u.z & 0xffff0000u), a[5]);
            a[6] = fmaf(v, __uint_as_float(u.w << 16), a[6]);
            a[7] = fmaf(v, __uint_as_float(u.w & 0xffff0000u), a[7]);
        }
        *reinterpret_cast<uint4*>(AGG + (size_t)r * DD + q * 8) = bf8_pack(a);
    }

    // stats: reduce the wave's 4 rows via shuffle; lanes<16 atomicAdd directly
    float s[8], sq[8];
    #pragma unroll
    for (int j = 0; j < 8; j++) { s[j] = a[j]; sq[j] = a[j] * a[j]; }
    #pragma unroll
    for (int j = 0; j < 8; j++) {
        s[j]  += __shfl_xor(s[j], 16);  sq[j] += __shfl_xor(sq[j], 16);
        s[j]  += __shfl_xor(s[j], 32);  sq[j] += __shfl_xor(sq[j], 32);
    }
    const int wl = t & 63;
    if (wl < 16) {
        int slotbase = ((blockIdx.x * 2 + (t >> 6)) & 63) * DD + wl * 8;
        #pragma unroll
        for (int j = 0; j < 8; j++) {
            atomicAdd(&psum[slotbase + j], s[j]);
            atomicAdd(&psq[slotbase + j], sq[j]);
        }
    }
}

extern "C" void kernel_launch(void* const* d_in, const int* in_sizes, int n_in,
                              void* d_out, int out_size, void* d_ws, size_t ws_size,
                              hipStream_t stream)
{
    const float* x_in     = (const float*)d_in[0];
    const int*   erow     = (const int*)d_in[1];
    const int*   ecol     = (const int*)d_in[2];
    const float* evalv    = (const float*)d_in[3];
    const float* gamma    = (const float*)d_in[4];
    const float* beta     = (const float*)d_in[5];
    const float* fc_in_w  = (const float*)d_in[6];
    const float* fc_in_b  = (const float*)d_in[7];
    const float* gc_w     = (const float*)d_in[8];
    // d_in[9] = gc_b: no-op under PairNorm (column-mean subtraction cancels it)
    const float* fc_out_w = (const float*)d_in[10];
    const float* fc_out_b = (const float*)d_in[11];
    float* out = (float*)d_out;

    const int n = in_sizes[0] / DD;   // 50000
    const int e = in_sizes[1];        // 800000
    const int NB = 512;
    const int nscan = (n + SCAN_TILE - 1) / SCAN_TILE;
    const int nbuk = (n + (1 << BSH) - 1) >> BSH;   // 98

    char* w = (char*)d_ws;
    // ---- zero region (single memset) ----
    char* zbase   = w;
    int* deg      = (int*)w;     w += (size_t)(n + 4) * 4;
    float* PSUMS  = (float*)w;   w += (size_t)4 * 64 * DD * 4;   // PN slots, per layer
    float* PSQS   = (float*)w;   w += (size_t)4 * 64 * DD * 4;
    const size_t zbytes = (size_t)(w - zbase);
    // ---- rest ----
    float* PSUM   = (float*)w;   w += (size_t)NB * DD * 4;       // BN partials (overwritten)
    float* PSQ    = (float*)w;   w += (size_t)NB * DD * 4;
    ushort* X     = (ushort*)w;  w += (size_t)n * DD * 2;
    ushort* Hb    = (ushort*)w;  w += (size_t)n * DD * 2;
    ushort* AGG   = (ushort*)w;  w += (size_t)n * DD * 2;
    float* AB     = (float*)w;   w += 2 * DD * 4;
    ushort* Wt    = (ushort*)w;  w += (size_t)4 * DD * DD * 2;
    ushort* Wtc   = (ushort*)w;  w += (size_t)DD * DD * 2;
    ushort* WtO   = (ushort*)w;  w += (size_t)48 * DD * 2;
    float* bc     = (float*)w;   w += DD * 4;
    int* rowptr   = (int*)w;     w += (size_t)(n + 4) * 4;
    int* cursor   = (int*)w;     w += (size_t)(n + 4) * 4;
    int* slocal   = (int*)w;     w += (size_t)(n + 4) * 4;
    int* bsum     = (int*)w;     w += 1024;
    int* bpre     = (int*)w;     w += 1024;
    int* gcur     = (int*)w;     w += 1024;
    uint2* binned = (uint2*)w;   w += (size_t)e * 8;
    int2* cpair   = (int2*)w;    w += (size_t)e * 8;

    hipMemsetAsync(zbase, 0, zbytes, stream);

    // ---- CSR build ----
    hist_k<<<(e + 255) / 256, 256, 0, stream>>>(erow, deg, e);
    scan1_k<<<nscan, 256, 0, stream>>>(deg, slocal, bsum, n);
    scan2_k<<<1, 256, 0, stream>>>(bsum, bpre, nscan, rowptr, n);
    scan3_k<<<nscan, 256, 0, stream>>>(slocal, bpre, rowptr, cursor, gcur, n);
    bin_a_k<<<(e + 2047) / 2048, 256, 0, stream>>>(erow, ecol, evalv, gcur, binned, e);
    bin_b_k<<<nbuk, 256, 0, stream>>>(binned, rowptr, cursor, cpair, n);

    // ---- all weight prep (one kernel) ----
    weights_k<<<130, 256, 0, stream>>>(gc_w, fc_in_w, fc_in_b, fc_out_w, Wt, Wtc, WtO, bc);

    // ---- BN stats ----
    col_reduce_k<<<NB, 256, 0, stream>>>(x_in, n, PSUM, PSQ);
    finalize_k<true><<<1, 1024, 0, stream>>>(PSUM, PSQ, NB, n, gamma, beta, AB);

    const int gblocks64 = (n + 63) / 64;
    const int sblocks = ((size_t)n * 16 + 127) / 128;

    // ---- layer 0: Hb = BN(x_in) @ (W_in@W0) + b@W0 ----
    gemm_mfma_k<1, 8, 128, true, true, false><<<gblocks64, 256, 0, stream>>>(
        x_in, Wtc, AB, bc, nullptr, Hb, DD, n);

    for (int l = 0; l < 4; l++) {
        spmm_fused_k<<<sblocks, 128, 0, stream>>>(rowptr, cpair, Hb, AGG,
            PSUMS + (size_t)l * 64 * DD, PSQS + (size_t)l * 64 * DD, n);
        finalize_k<false><<<1, 1024, 0, stream>>>(PSUMS + (size_t)l * 64 * DD,
            PSQS + (size_t)l * 64 * DD, 64, n, nullptr, nullptr, AB);
        if (l < 3) {
            if (l == 0)
                gemm_mfma_k<2, 8, 128, false, true, true><<<gblocks64, 256, 0, stream>>>(
                    AGG, Wt + (size_t)(l + 1) * DD * DD, AB, nullptr, X, Hb, DD, n);
            else
                gemm_mfma_k<3, 8, 128, false, true, true><<<gblocks64, 256, 0, stream>>>(
                    AGG, Wt + (size_t)(l + 1) * DD * DD, AB, nullptr, X, Hb, DD, n);
        } else {
            gemm_mfma_k<3, 3, 40, true, false, false><<<gblocks64, 256, 0, stream>>>(
                AGG, WtO, AB, fc_out_b, X, out, 40, n);
        }
    }
}

// Round 14
// 390.549 us; speedup vs baseline: 1.9909x; 1.9909x over previous
//
#include <hip/hip_runtime.h>
#include <hip/hip_bf16.h>

// DeepGCN forward (R13 = R9 + 128-row GEMM tiles):
//   memset(zeros) -> hist -> scan1/2/3(+gcur) -> bin_a -> bin_b -> weights_k ->
//   col_reduce -> finalize<BN> -> L0 GEMM (composite W_in@W0) ->
//   4x [ spmm(R9 body: 256-thr, LDS-combined stats, 1 atomic/col/block) ->
//        finalize<PN> -> GEMM(128-row tile, fused PN+ReLU+residual) ] ; fc_out GEMM.
// R12 post-mortem: barrier-free per-wave atomics = 4x device-scope RMW to one hot
//   64KB region -> cross-XCD serialization + 97MB write inflation (42->158us). REVERT.
// R13: GEMM blocks 64->128 rows: halves redundant W staging (782->391 blocks),
//   2x MFMA per stage barrier, B-fragment reused across 2 row-fragments.

constexpr int DD = 128;

struct alignas(16) f4 { float v[4]; };
typedef unsigned short ushort;
typedef unsigned int uint;
typedef short short8 __attribute__((ext_vector_type(8)));
typedef float f32x4 __attribute__((ext_vector_type(4)));

__device__ inline ushort f2bf(float f) {   // RNE f32->bf16
    uint u = __float_as_uint(f);
    u += 0x7fffu + ((u >> 16) & 1u);
    return (ushort)(u >> 16);
}
__device__ inline void bf8_unpack(uint4 u, float* v) {
    v[0] = __uint_as_float(u.x << 16); v[1] = __uint_as_float(u.x & 0xffff0000u);
    v[2] = __uint_as_float(u.y << 16); v[3] = __uint_as_float(u.y & 0xffff0000u);
    v[4] = __uint_as_float(u.z << 16); v[5] = __uint_as_float(u.z & 0xffff0000u);
    v[6] = __uint_as_float(u.w << 16); v[7] = __uint_as_float(u.w & 0xffff0000u);
}
__device__ inline uint4 bf8_pack(const float* v) {
    uint4 o;
    o.x = (uint)f2bf(v[0]) | ((uint)f2bf(v[1]) << 16);
    o.y = (uint)f2bf(v[2]) | ((uint)f2bf(v[3]) << 16);
    o.z = (uint)f2bf(v[4]) | ((uint)f2bf(v[5]) << 16);
    o.w = (uint)f2bf(v[6]) | ((uint)f2bf(v[7]) << 16);
    return o;
}

// ---------------- BN stats over x_in: per-block partials ----------------
__global__ __launch_bounds__(256) void col_reduce_k(const float* __restrict__ X, int n,
    float* __restrict__ psum, float* __restrict__ psq)
{
    int c = threadIdx.x & (DD - 1);
    int half = threadIdx.x >> 7;
    int rows_per_blk = (n + gridDim.x - 1) / gridDim.x;
    int r0 = blockIdx.x * rows_per_blk;
    int r1 = min(n, r0 + rows_per_blk);
    float s = 0.f, ss = 0.f;
    for (int r = r0 + half; r < r1; r += 2) {
        float v = X[(size_t)r * DD + c];
        s += v; ss += v * v;
    }
    __shared__ float ls[256], lq[256];
    ls[threadIdx.x] = s; lq[threadIdx.x] = ss;
    __syncthreads();
    if (half == 0) {
        psum[blockIdx.x * DD + c] = ls[c] + ls[c + 128];
        psq [blockIdx.x * DD + c] = lq[c] + lq[c + 128];
    }
}

// ---------------- finalize (BN or PN) ----------------
template<bool BN>
__global__ __launch_bounds__(1024) void finalize_k(const float* __restrict__ psum,
    const float* __restrict__ psq, int nblk, int n,
    const float* __restrict__ gamma, const float* __restrict__ beta,
    float* __restrict__ AB)
{
    const int c = threadIdx.x & (DD - 1);
    const int g = threadIdx.x >> 7;   // 0..7
    float s = 0.f, ss = 0.f;
    for (int b = g; b < nblk; b += 8) {
        s  += psum[b * DD + c];
        ss += psq [b * DD + c];
    }
    __shared__ float Ls[8][DD], Lq[8][DD];
    Ls[g][c] = s; Lq[g][c] = ss;
    __syncthreads();
    float ts = 0.f, tss = 0.f;
    #pragma unroll
    for (int k = 0; k < 8; k++) { ts += Ls[k][c]; tss += Lq[k][c]; }
    float mu = ts / (float)n;
    if (BN) {
        if (threadIdx.x < DD) {
            float var = tss / (float)n - mu * mu;
            float a = gamma[c] * rsqrtf(var + 1e-5f);
            AB[c] = a;
            AB[DD + c] = beta[c] - mu * a;
        }
    } else {
        float cent = tss - (float)n * mu * mu;
        __syncthreads();
        if (g == 0) Ls[0][c] = cent;
        __syncthreads();
        for (int off = 64; off > 0; off >>= 1) {
            if (threadIdx.x < off) Ls[0][threadIdx.x] += Ls[0][threadIdx.x + off];
            __syncthreads();
        }
        if (threadIdx.x < DD) {
            float inv = rsqrtf(1e-6f + Ls[0][0] / (float)n);
            AB[c] = inv;
            AB[DD + c] = -mu * inv;
        }
    }
}

// ---------------- all weight prep in one kernel (role by blockIdx) ----------------
__global__ __launch_bounds__(256) void weights_k(const float* __restrict__ gc_w,
    const float* __restrict__ fc_in_w, const float* __restrict__ fc_in_b,
    const float* __restrict__ fc_out_w,
    ushort* __restrict__ Wt, ushort* __restrict__ Wtc, ushort* __restrict__ WtO,
    float* __restrict__ bc)
{
    const int b = blockIdx.x;
    const int t = threadIdx.x;
    if (b < 64) {
        int w = b >> 4, tile = b & 15;
        int tr = (tile >> 2) * 32, tc = (tile & 3) * 32;
        const float* W = gc_w + (size_t)w * DD * DD;
        ushort* Wo = Wt + (size_t)w * DD * DD;
        __shared__ float tls[32][33];
        int tx = t & 31, ty = t >> 5;  // 32 x 8
        #pragma unroll
        for (int j = 0; j < 32; j += 8)
            tls[ty + j][tx] = W[(size_t)(tr + ty + j) * DD + tc + tx];
        __syncthreads();
        #pragma unroll
        for (int j = 0; j < 32; j += 8)
            Wo[(size_t)(tc + ty + j) * DD + (tr + tx)] = f2bf(tls[tx][ty + j]);
    } else if (b == 64) {
        for (int i = t; i < 48 * DD; i += 256) {
            int nn = i >> 7, k = i & 127;
            float v = (nn < 40) ? fc_out_w[(size_t)k * 40 + nn] : 0.f;
            WtO[i] = f2bf(v);
        }
    } else if (b == 65) {
        if (t < DD) {
            float acc = 0.f;
            for (int j = 0; j < DD; j++) acc += fc_in_b[j] * gc_w[(size_t)j * DD + t];
            bc[t] = acc;
        }
    } else {
        int idx = (b - 66) * 256 + t;
        int nn = idx & 127, k = idx >> 7;
        float acc = 0.f;
        for (int j = 0; j < DD; j++)
            acc += fc_in_w[(size_t)k * DD + j] * gc_w[(size_t)j * DD + nn];
        Wtc[(size_t)nn * DD + k] = f2bf(acc);
    }
}

// ---------------- MFMA GEMM, 128-row tiles, fused pre-stage ----------------
// PRE: 1=f32 BN affine, 2=bf16-in PN relu(x*A+B), 3=PN + residual (bf16 X)
template<int PRE, int NCOLF, int NCOLW, bool BIAS, bool OUTBF, bool WRITEX>
__global__ __launch_bounds__(256) void gemm_mfma_k(const void* __restrict__ INv,
    const ushort* __restrict__ Wt, const float* __restrict__ AB,
    const float* __restrict__ bias, void* __restrict__ Xresv,
    void* __restrict__ Yout, int ystride, int n)
{
    __shared__ short xs[128][136];           // [m][k] bf16 (pad 136)
    __shared__ short ws[NCOLF * 16][136];    // [n][k] bf16
    __shared__ float bias_s[DD];
    const int t = threadIdx.x;
    if (BIAS && t < NCOLW) bias_s[t] = bias[t];

    const int row0 = blockIdx.x * 128;
    if (PRE <= 1) {
        const float* IN = (const float*)INv;
        for (int i = t; i < 128 * 32; i += 256) {
            int m = i >> 5, koff = (i & 31) << 2;
            int r = row0 + m;
            f4 v; v.v[0] = v.v[1] = v.v[2] = v.v[3] = 0.f;
            if (r < n) {
                v = *reinterpret_cast<const f4*>(IN + (size_t)r * DD + koff);
                #pragma unroll
                for (int j = 0; j < 4; j++) v.v[j] = v.v[j] * AB[koff + j] + AB[DD + koff + j];
            }
            uint2 p;
            p.x = (uint)f2bf(v.v[0]) | ((uint)f2bf(v.v[1]) << 16);
            p.y = (uint)f2bf(v.v[2]) | ((uint)f2bf(v.v[3]) << 16);
            *reinterpret_cast<uint2*>(&xs[m][koff]) = p;
        }
    } else {
        const ushort* IN = (const ushort*)INv;
        ushort* Xres = (ushort*)Xresv;
        for (int i = t; i < 128 * 16; i += 256) {
            int m = i >> 4, k8 = (i & 15) << 3;
            int r = row0 + m;
            float v[8];
            if (r < n) {
                uint4 u = *reinterpret_cast<const uint4*>(IN + (size_t)r * DD + k8);
                bf8_unpack(u, v);
                #pragma unroll
                for (int j = 0; j < 8; j++)
                    v[j] = fmaxf(v[j] * AB[k8 + j] + AB[DD + k8 + j], 0.f);
                if (PRE == 3) {
                    uint4 xo = *reinterpret_cast<const uint4*>(Xres + (size_t)r * DD + k8);
                    float xov[8]; bf8_unpack(xo, xov);
                    #pragma unroll
                    for (int j = 0; j < 8; j++) v[j] += xov[j];
                }
                uint4 pk = bf8_pack(v);
                if (WRITEX)
                    *reinterpret_cast<uint4*>(Xres + (size_t)r * DD + k8) = pk;
                *reinterpret_cast<uint4*>(&xs[m][k8]) = pk;
            } else {
                uint4 z; z.x = z.y = z.z = z.w = 0u;
                *reinterpret_cast<uint4*>(&xs[m][k8]) = z;
            }
        }
    }
    for (int i = t; i < NCOLF * 256; i += 256) {
        int nn = i >> 4, koff = (i & 15) << 3;
        *reinterpret_cast<uint4*>(&ws[nn][koff]) =
            *reinterpret_cast<const uint4*>(Wt + (size_t)nn * DD + koff);
    }
    __syncthreads();

    const int wave = t >> 6, lane = t & 63, fr = lane & 15, g = lane >> 4;
    f32x4 acc[2][NCOLF];
    #pragma unroll
    for (int m = 0; m < 2; m++)
        #pragma unroll
        for (int c = 0; c < NCOLF; c++) acc[m][c] = (f32x4){0.f, 0.f, 0.f, 0.f};

    #pragma unroll 2
    for (int ks = 0; ks < 4; ks++) {
        int k0 = ks * 32 + g * 8;
        short8 a0 = *reinterpret_cast<const short8*>(&xs[wave * 32 + fr][k0]);
        short8 a1 = *reinterpret_cast<const short8*>(&xs[wave * 32 + 16 + fr][k0]);
        #pragma unroll
        for (int c = 0; c < NCOLF; c++) {
            short8 b = *reinterpret_cast<const short8*>(&ws[c * 16 + fr][k0]);
            // mfma(W_frag, X_frag): out lane&15 = X-row (m), g*4+reg = W-col (n)
            acc[0][c] = __builtin_amdgcn_mfma_f32_16x16x32_bf16(b, a0, acc[0][c], 0, 0, 0);
            acc[1][c] = __builtin_amdgcn_mfma_f32_16x16x32_bf16(b, a1, acc[1][c], 0, 0, 0);
        }
    }

    #pragma unroll
    for (int m = 0; m < 2; m++) {
        const int row = row0 + wave * 32 + m * 16 + fr;
        if (row < n) {
            #pragma unroll
            for (int c = 0; c < NCOLF; c++) {
                int n0 = c * 16 + g * 4;
                if (OUTBF) {
                    float b0 = BIAS ? bias_s[n0 + 0] : 0.f, b1 = BIAS ? bias_s[n0 + 1] : 0.f;
                    float b2 = BIAS ? bias_s[n0 + 2] : 0.f, b3 = BIAS ? bias_s[n0 + 3] : 0.f;
                    uint2 o;
                    o.x = (uint)f2bf(acc[m][c][0] + b0) | ((uint)f2bf(acc[m][c][1] + b1) << 16);
                    o.y = (uint)f2bf(acc[m][c][2] + b2) | ((uint)f2bf(acc[m][c][3] + b3) << 16);
                    *reinterpret_cast<uint2*>((ushort*)Yout + (size_t)row * DD + n0) = o;
                } else if (n0 + 3 < NCOLW) {
                    f4 o;
                    #pragma unroll
                    for (int j = 0; j < 4; j++)
                        o.v[j] = acc[m][c][j] + (BIAS ? bias_s[n0 + j] : 0.f);
                    *reinterpret_cast<f4*>((float*)Yout + (size_t)row * ystride + n0) = o;
                }
            }
        }
    }
}

// ---------------- CSR build ----------------
__global__ __launch_bounds__(256) void hist_k(const int* __restrict__ erow,
    int* __restrict__ deg, int e)
{
    int i = blockIdx.x * 256 + threadIdx.x;
    if (i < e) atomicAdd(&deg[erow[i]], 1);
}

constexpr int SCAN_TILE = 1024;
constexpr int BSH = 9;                 // 512-row buckets

__global__ __launch_bounds__(256) void scan1_k(const int* __restrict__ deg,
    int* __restrict__ local, int* __restrict__ bsum, int n)
{
    const int t = threadIdx.x;
    const int base = blockIdx.x * SCAN_TILE + t * 4;
    int v0 = 0, v1 = 0, v2 = 0, v3 = 0;
    if (base + 3 < n) {
        int4 v = *reinterpret_cast<const int4*>(deg + base);
        v0 = v.x; v1 = v.y; v2 = v.z; v3 = v.w;
    } else {
        if (base + 0 < n) v0 = deg[base + 0];
        if (base + 1 < n) v1 = deg[base + 1];
        if (base + 2 < n) v2 = deg[base + 2];
        if (base + 3 < n) v3 = deg[base + 3];
    }
    int s = v0 + v1 + v2 + v3;
    __shared__ int ps[256];
    ps[t] = s;
    __syncthreads();
    for (int off = 1; off < 256; off <<= 1) {
        int add = (t >= off) ? ps[t - off] : 0;
        __syncthreads();
        ps[t] += add;
        __syncthreads();
    }
    int excl = (t > 0) ? ps[t - 1] : 0;
    int o0 = excl, o1 = excl + v0, o2 = o1 + v1, o3 = o2 + v2;
    if (base + 3 < n) {
        int4 o; o.x = o0; o.y = o1; o.z = o2; o.w = o3;
        *reinterpret_cast<int4*>(local + base) = o;
    } else {
        if (base + 0 < n) local[base + 0] = o0;
        if (base + 1 < n) local[base + 1] = o1;
        if (base + 2 < n) local[base + 2] = o2;
        if (base + 3 < n) local[base + 3] = o3;
    }
    if (t == 255) bsum[blockIdx.x] = ps[255];
}

__global__ __launch_bounds__(256) void scan2_k(const int* __restrict__ bsum,
    int* __restrict__ bpre, int nb, int* __restrict__ rowptr, int n)
{
    const int t = threadIdx.x;
    __shared__ int ps[256];
    ps[t] = (t < nb) ? bsum[t] : 0;
    __syncthreads();
    for (int off = 1; off < 256; off <<= 1) {
        int add = (t >= off) ? ps[t - off] : 0;
        __syncthreads();
        ps[t] += add;
        __syncthreads();
    }
    if (t < nb) bpre[t] = (t > 0) ? ps[t - 1] : 0;
    if (t == 255) rowptr[n] = ps[255];
}

// also writes gcur[] at 512-row bucket boundaries (folded gcur_init)
__global__ __launch_bounds__(256) void scan3_k(const int* __restrict__ local,
    const int* __restrict__ bpre, int* __restrict__ rowptr, int* __restrict__ cursor,
    int* __restrict__ gcur, int n)
{
    const int base = blockIdx.x * SCAN_TILE + threadIdx.x * 4;
    const int p = bpre[blockIdx.x];
    if (base + 3 < n) {
        int4 v = *reinterpret_cast<const int4*>(local + base);
        v.x += p; v.y += p; v.z += p; v.w += p;
        *reinterpret_cast<int4*>(rowptr + base) = v;
        *reinterpret_cast<int4*>(cursor + base) = v;
        if ((base & 511) == 0) gcur[base >> BSH] = v.x;
    } else {
        #pragma unroll
        for (int j = 0; j < 4; j++)
            if (base + j < n) {
                int v = local[base + j] + p;
                rowptr[base + j] = v;
                cursor[base + j] = v;
                if (((base + j) & 511) == 0) gcur[(base + j) >> BSH] = v;
            }
    }
}

// pass A: bin edges by 512-row bucket (LDS rank; bucket-contiguous 8B writes)
__global__ __launch_bounds__(256) void bin_a_k(const int* __restrict__ erow,
    const int* __restrict__ ecol, const float* __restrict__ evalv,
    int* __restrict__ gcur, uint2* __restrict__ binned, int e)
{
    __shared__ int cnt[128];
    __shared__ int base[128];
    const int t = threadIdx.x;
    if (t < 128) cnt[t] = 0;
    __syncthreads();
    const int i0 = blockIdx.x * 2048 + t * 8;
    int rw[8], cl[8], rk[8];
    float vl[8];
    #pragma unroll
    for (int j = 0; j < 8; j++) {
        int idx = i0 + j;
        if (idx < e) { rw[j] = erow[idx]; cl[j] = ecol[idx]; vl[j] = evalv[idx]; }
        else rw[j] = -1;
    }
    #pragma unroll
    for (int j = 0; j < 8; j++)
        if (rw[j] >= 0) rk[j] = atomicAdd(&cnt[rw[j] >> BSH], 1);
    __syncthreads();
    if (t < 128) base[t] = cnt[t] ? atomicAdd(&gcur[t], cnt[t]) : 0;
    __syncthreads();
    #pragma unroll
    for (int j = 0; j < 8; j++) {
        if (rw[j] >= 0) {
            int b = rw[j] >> BSH, rl = rw[j] & ((1 << BSH) - 1);
            uint2 pr;
            pr.x = (uint)cl[j] | ((uint)rl << 16);
            pr.y = __float_as_uint(vl[j]);
            binned[base[b] + rk[j]] = pr;
        }
    }
}

// pass B: within-bucket scatter to CSR position (dest region ~64KB -> L2-resident)
__global__ __launch_bounds__(256) void bin_b_k(const uint2* __restrict__ binned,
    const int* __restrict__ rowptr, int* __restrict__ cursor,
    int2* __restrict__ cpair, int n)
{
    const int b = blockIdx.x;
    const int r0 = min(b << BSH, n), r1 = min((b + 1) << BSH, n);
    const int p0 = rowptr[r0], p1 = rowptr[r1];
    for (int p = p0 + threadIdx.x; p < p1; p += 256) {
        uint2 u = binned[p];
        int r = (b << BSH) + (int)(u.x >> 16);
        int pos = atomicAdd(&cursor[r], 1);
        int2 pr; pr.x = (int)(u.x & 0xffffu); pr.y = (int)u.y;
        cpair[pos] = pr;
    }
}

// ---------------- SpMM (bf16 gather) + fused column stats (R9 body) ----------------
__global__ __launch_bounds__(256) void spmm_fused_k(const int* __restrict__ rowptr,
    const int2* __restrict__ cpair, const ushort* __restrict__ H,
    ushort* __restrict__ AGG, float* __restrict__ psum, float* __restrict__ psq, int n)
{
    const int t = threadIdx.x;
    const int gid = blockIdx.x * 256 + t;
    const int r = gid >> 4;
    const int q = t & 15;
    float a[8];
    #pragma unroll
    for (int j = 0; j < 8; j++) a[j] = 0.f;

    if (r < n) {
        int p0 = rowptr[r], p1 = rowptr[r + 1];
        const ushort* Hq = H + q * 8;
        int p = p0;
        for (; p + 8 <= p1; p += 8) {             // 8-deep MLP
            int2 c[8];
            #pragma unroll
            for (int j = 0; j < 8; j++) c[j] = cpair[p + j];
            uint4 u[8];
            #pragma unroll
            for (int j = 0; j < 8; j++)
                u[j] = *reinterpret_cast<const uint4*>(Hq + (size_t)c[j].x * DD);
            #pragma unroll
            for (int j = 0; j < 8; j++) {
                float v = __int_as_float(c[j].y);
                a[0] = fmaf(v, __uint_as_float(u[j].x << 16), a[0]);
                a[1] = fmaf(v, __uint_as_float(u[j].x & 0xffff0000u), a[1]);
                a[2] = fmaf(v, __uint_as_float(u[j].y << 16), a[2]);
                a[3] = fmaf(v, __uint_as_float(u[j].y & 0xffff0000u), a[3]);
                a[4] = fmaf(v, __uint_as_float(u[j].z << 16), a[4]);
                a[5] = fmaf(v, __uint_as_float(u[j].z & 0xffff0000u), a[5]);
                a[6] = fmaf(v, __uint_as_float(u[j].w << 16), a[6]);
                a[7] = fmaf(v, __uint_as_float(u[j].w & 0xffff0000u), a[7]);
            }
        }
        if (p + 4 <= p1) {                        // 4-deep
            int2 c[4];
            #pragma unroll
            for (int j = 0; j < 4; j++) c[j] = cpair[p + j];
            uint4 u[4];
            #pragma unroll
            for (int j = 0; j < 4; j++)
                u[j] = *reinterpret_cast<const uint4*>(Hq + (size_t)c[j].x * DD);
            #pragma unroll
            for (int j = 0; j < 4; j++) {
                float v = __int_as_float(c[j].y);
                a[0] = fmaf(v, __uint_as_float(u[j].x << 16), a[0]);
                a[1] = fmaf(v, __uint_as_float(u[j].x & 0xffff0000u), a[1]);
                a[2] = fmaf(v, __uint_as_float(u[j].y << 16), a[2]);
                a[3] = fmaf(v, __uint_as_float(u[j].y & 0xffff0000u), a[3]);
                a[4] = fmaf(v, __uint_as_float(u[j].z << 16), a[4]);
                a[5] = fmaf(v, __uint_as_float(u[j].z & 0xffff0000u), a[5]);
                a[6] = fmaf(v, __uint_as_float(u[j].w << 16), a[6]);
                a[7] = fmaf(v, __uint_as_float(u[j].w & 0xffff0000u), a[7]);
            }
            p += 4;
        }
        for (; p < p1; p++) {                     // tail
            int2 cv = cpair[p];
            float v = __int_as_float(cv.y);
            uint4 u = *reinterpret_cast<const uint4*>(Hq + (size_t)cv.x * DD);
            a[0] = fmaf(v, __uint_as_float(u.x << 16), a[0]);
            a[1] = fmaf(v, __uint_as_float(u.x & 0xffff0000u), a[1]);
            a[2] = fmaf(v, __uint_as_float(u.y << 16), a[2]);
            a[3] = fmaf(v, __uint_as_float(u.y & 0xffff0000u), a[3]);
            a[4] = fmaf(v, __uint_as_float(u.z << 16), a[4]);
            a[5] = fmaf(v, __uint_as_float(u.z & 0xffff0000u), a[5]);
            a[6] = fmaf(v, __uint_as_float(u.w << 16), a[6]);
            a[7] = fmaf(v, __uint_as_float(u.w & 0xffff0000u), a[7]);
        }
        *reinterpret_cast<uint4*>(AGG + (size_t)r * DD + q * 8) = bf8_pack(a);
    }

    // column stats: 4 rows per wave via shuffle, 4 waves via LDS, atomic into 64 slots
    float s[8], sq[8];
    #pragma unroll
    for (int j = 0; j < 8; j++) { s[j] = a[j]; sq[j] = a[j] * a[j]; }
    #pragma unroll
    for (int j = 0; j < 8; j++) {
        s[j]  += __shfl_xor(s[j], 16);  sq[j] += __shfl_xor(sq[j], 16);
        s[j]  += __shfl_xor(s[j], 32);  sq[j] += __shfl_xor(sq[j], 32);
    }
    __shared__ float sA[4][DD], qA[4][DD];
    const int wave = t >> 6, lane = t & 63;
    if (lane < 16) {
        #pragma unroll
        for (int j = 0; j < 8; j++) {
            sA[wave][lane * 8 + j] = s[j];
            qA[wave][lane * 8 + j] = sq[j];
        }
    }
    __syncthreads();
    if (t < DD) {
        float S = 0.f, Q = 0.f;
        #pragma unroll
        for (int w = 0; w < 4; w++) { S += sA[w][t]; Q += qA[w][t]; }
        int slot = (blockIdx.x & 63) * DD + t;
        atomicAdd(&psum[slot], S);
        atomicAdd(&psq[slot], Q);
    }
}

extern "C" void kernel_launch(void* const* d_in, const int* in_sizes, int n_in,
                              void* d_out, int out_size, void* d_ws, size_t ws_size,
                              hipStream_t stream)
{
    const float* x_in     = (const float*)d_in[0];
    const int*   erow     = (const int*)d_in[1];
    const int*   ecol     = (const int*)d_in[2];
    const float* evalv    = (const float*)d_in[3];
    const float* gamma    = (const float*)d_in[4];
    const float* beta     = (const float*)d_in[5];
    const float* fc_in_w  = (const float*)d_in[6];
    const float* fc_in_b  = (const float*)d_in[7];
    const float* gc_w     = (const float*)d_in[8];
    // d_in[9] = gc_b: no-op under PairNorm (column-mean subtraction cancels it)
    const float* fc_out_w = (const float*)d_in[10];
    const float* fc_out_b = (const float*)d_in[11];
    float* out = (float*)d_out;

    const int n = in_sizes[0] / DD;   // 50000
    const int e = in_sizes[1];        // 800000
    const int NB = 512;
    const int nscan = (n + SCAN_TILE - 1) / SCAN_TILE;
    const int nbuk = (n + (1 << BSH) - 1) >> BSH;   // 98

    char* w = (char*)d_ws;
    // ---- zero region (single memset) ----
    char* zbase   = w;
    int* deg      = (int*)w;     w += (size_t)(n + 4) * 4;
    float* PSUMS  = (float*)w;   w += (size_t)4 * 64 * DD * 4;   // PN slots, per layer
    float* PSQS   = (float*)w;   w += (size_t)4 * 64 * DD * 4;
    const size_t zbytes = (size_t)(w - zbase);
    // ---- rest ----
    float* PSUM   = (float*)w;   w += (size_t)NB * DD * 4;       // BN partials (overwritten)
    float* PSQ    = (float*)w;   w += (size_t)NB * DD * 4;
    ushort* X     = (ushort*)w;  w += (size_t)n * DD * 2;
    ushort* Hb    = (ushort*)w;  w += (size_t)n * DD * 2;
    ushort* AGG   = (ushort*)w;  w += (size_t)n * DD * 2;
    float* AB     = (float*)w;   w += 2 * DD * 4;
    ushort* Wt    = (ushort*)w;  w += (size_t)4 * DD * DD * 2;
    ushort* Wtc   = (ushort*)w;  w += (size_t)DD * DD * 2;
    ushort* WtO   = (ushort*)w;  w += (size_t)48 * DD * 2;
    float* bc     = (float*)w;   w += DD * 4;
    int* rowptr   = (int*)w;     w += (size_t)(n + 4) * 4;
    int* cursor   = (int*)w;     w += (size_t)(n + 4) * 4;
    int* slocal   = (int*)w;     w += (size_t)(n + 4) * 4;
    int* bsum     = (int*)w;     w += 1024;
    int* bpre     = (int*)w;     w += 1024;
    int* gcur     = (int*)w;     w += 1024;
    uint2* binned = (uint2*)w;   w += (size_t)e * 8;
    int2* cpair   = (int2*)w;    w += (size_t)e * 8;

    hipMemsetAsync(zbase, 0, zbytes, stream);

    // ---- CSR build ----
    hist_k<<<(e + 255) / 256, 256, 0, stream>>>(erow, deg, e);
    scan1_k<<<nscan, 256, 0, stream>>>(deg, slocal, bsum, n);
    scan2_k<<<1, 256, 0, stream>>>(bsum, bpre, nscan, rowptr, n);
    scan3_k<<<nscan, 256, 0, stream>>>(slocal, bpre, rowptr, cursor, gcur, n);
    bin_a_k<<<(e + 2047) / 2048, 256, 0, stream>>>(erow, ecol, evalv, gcur, binned, e);
    bin_b_k<<<nbuk, 256, 0, stream>>>(binned, rowptr, cursor, cpair, n);

    // ---- all weight prep (one kernel) ----
    weights_k<<<130, 256, 0, stream>>>(gc_w, fc_in_w, fc_in_b, fc_out_w, Wt, Wtc, WtO, bc);

    // ---- BN stats ----
    col_reduce_k<<<NB, 256, 0, stream>>>(x_in, n, PSUM, PSQ);
    finalize_k<true><<<1, 1024, 0, stream>>>(PSUM, PSQ, NB, n, gamma, beta, AB);

    const int gblocks128 = (n + 127) / 128;
    const int sblocks = ((size_t)n * 16 + 255) / 256;

    // ---- layer 0: Hb = BN(x_in) @ (W_in@W0) + b@W0 ----
    gemm_mfma_k<1, 8, 128, true, true, false><<<gblocks128, 256, 0, stream>>>(
        x_in, Wtc, AB, bc, nullptr, Hb, DD, n);

    for (int l = 0; l < 4; l++) {
        spmm_fused_k<<<sblocks, 256, 0, stream>>>(rowptr, cpair, Hb, AGG,
            PSUMS + (size_t)l * 64 * DD, PSQS + (size_t)l * 64 * DD, n);
        finalize_k<false><<<1, 1024, 0, stream>>>(PSUMS + (size_t)l * 64 * DD,
            PSQS + (size_t)l * 64 * DD, 64, n, nullptr, nullptr, AB);
        if (l < 3) {
            if (l == 0)
                gemm_mfma_k<2, 8, 128, false, true, true><<<gblocks128, 256, 0, stream>>>(
                    AGG, Wt + (size_t)(l + 1) * DD * DD, AB, nullptr, X, Hb, DD, n);
            else
                gemm_mfma_k<3, 8, 128, false, true, true><<<gblocks128, 256, 0, stream>>>(
                    AGG, Wt + (size_t)(l + 1) * DD * DD, AB, nullptr, X, Hb, DD, n);
        } else {
            gemm_mfma_k<3, 3, 40, true, false, false><<<gblocks128, 256, 0, stream>>>(
                AGG, WtO, AB, fc_out_b, X, out, 40, n);
        }
    }
}